// Round 3
// baseline (452.223 us; speedup 1.0000x reference)
//
#include <hip/hip_runtime.h>
#include <cstddef>

#define NN 8192
#define CC 128

// ---------------- CSR build ----------------

__global__ __launch_bounds__(256) void count_deg_int_k(const int* __restrict__ dst, int* degi, int E) {
  int i = blockIdx.x * 256 + threadIdx.x;
  if (i < E) atomicAdd(&degi[dst[i]], 1);
}

__global__ __launch_bounds__(256) void dinv_k(const int* __restrict__ degi, float* __restrict__ dinv, int n) {
  int i = blockIdx.x * 256 + threadIdx.x;
  if (i < n) dinv[i] = rsqrtf((float)(degi[i] + 1));  // +1 self loop; always >= 1
}

__global__ __launch_bounds__(256) void scan_k(const int* __restrict__ degi, int* __restrict__ rowstart,
                                              int* __restrict__ cursor) {
  __shared__ int partial[256];
  int t = threadIdx.x;
  int base = t * 32;
  int local[32];
  int s = 0;
#pragma unroll
  for (int i = 0; i < 32; ++i) { local[i] = s; s += degi[base + i]; }
  partial[t] = s;
  __syncthreads();
  for (int off = 1; off < 256; off <<= 1) {
    int v = (t >= off) ? partial[t - off] : 0;
    __syncthreads();
    partial[t] += v;
    __syncthreads();
  }
  int offset = partial[t] - s;  // exclusive
#pragma unroll
  for (int i = 0; i < 32; ++i) {
    rowstart[base + i] = offset + local[i];
    cursor[base + i] = offset + local[i];
  }
  if (t == 255) rowstart[NN] = offset + s;
}

__global__ __launch_bounds__(256) void bucket_k(const int* __restrict__ src, const int* __restrict__ dst,
    int* __restrict__ cursor, int* __restrict__ col, int E) {
  int e = blockIdx.x * 256 + threadIdx.x;
  if (e >= E) return;
  int d = dst[e];
  int pos = atomicAdd(&cursor[d], 1);
  col[pos] = src[e];
}

// h1 = sum_in-edges xw[s]*dinv[s]*dinv[d] + xw[d]*dinv[d]^2 + conv_b + x
__global__ __launch_bounds__(256) void gather_k(const int* __restrict__ rowstart, const int* __restrict__ col,
    const float* __restrict__ xw, const float* __restrict__ dinv, const float* __restrict__ cb,
    const float* __restrict__ x, float* __restrict__ h1) {
  int d = blockIdx.x * 2 + (threadIdx.x >> 7);
  int c = threadIdx.x & 127;
  int j0 = rowstart[d], j1 = rowstart[d + 1];
  float dd = dinv[d];
  float sum = 0.f;
  int s_next = (j0 < j1) ? col[j0] : 0;
  for (int j = j0; j < j1; ++j) {
    int s = s_next;
    if (j + 1 < j1) s_next = col[j + 1];
    sum += xw[(size_t)s * CC + c] * dinv[s];
  }
  sum *= dd;
  int idx = d * CC + c;
  sum += xw[idx] * dd * dd;      // self loop
  h1[idx] = sum + cb[c] + x[idx];
}

// ---------------- BN helpers ----------------

__global__ __launch_bounds__(256) void bn_stats_k(const float* __restrict__ X,
    float* __restrict__ sums, float* __restrict__ sumsq) {
  int t = threadIdx.x;
  int c = t & 127, rg = t >> 7;
  int r0 = blockIdx.x * 64;
  float s = 0.f, sq = 0.f;
  for (int i = 0; i < 32; ++i) {
    float v = X[(size_t)(r0 + rg + 2 * i) * CC + c];
    s += v; sq += v * v;
  }
  atomicAdd(&sums[c], s);
  atomicAdd(&sumsq[c], sq);
}

__global__ void bn_finalize_k(const float* sums, const float* sumsq, const float* g, const float* be,
                              float* scale, float* shift) {
  int c = threadIdx.x;
  float mu = sums[c] * (1.0f / NN);
  float var = sumsq[c] * (1.0f / NN) - mu * mu;
  float sc = g[c] * rsqrtf(var + 1e-5f);
  scale[c] = sc;
  shift[c] = be[c] - mu * sc;
}

__global__ __launch_bounds__(256) void combine_k(const float* __restrict__ h1, const float* __restrict__ h2,
    const float* __restrict__ sc0, const float* __restrict__ sh0,
    const float* __restrict__ sc1, const float* __restrict__ sh1, float* __restrict__ out) {
  int idx = blockIdx.x * 256 + threadIdx.x;
  int c = idx & 127;
  out[idx] = sc0[c] * h1[idx] + sh0[c] + sc1[c] * h2[idx] + sh1[c];
}

__global__ __launch_bounds__(256) void bn_apply_k(const float* __restrict__ h, const float* __restrict__ sc,
    const float* __restrict__ sh, float* __restrict__ out) {
  int idx = blockIdx.x * 256 + threadIdx.x;
  int c = idx & 127;
  out[idx] = sc[c] * h[idx] + sh[c];
}

// ---------------- fp32 GEMM (As padded 128->132: kills 4-way A-tile read conflicts) ----------------
__global__ __launch_bounds__(256) void gemm_k(const float* __restrict__ A, const float* __restrict__ W,
    const float* __restrict__ bias, const float* __restrict__ resid, float* __restrict__ out,
    int M, int N, int K, float scale, int relu) {
  __shared__ float As[64 * 132];
  __shared__ float Ws[128 * 64];
  int t = threadIdx.x;
  int ty = t >> 4, tx = t & 15;
  int row0 = blockIdx.x * 64, n0 = blockIdx.y * 64;
  float acc[4][4] = {};
  for (int kc = 0; kc < K; kc += 128) {
#pragma unroll
    for (int j = 0; j < 8; ++j) {
      int f = t + 256 * j;
      int r = f >> 5, c4 = f & 31;
      *(float4*)(As + r * 132 + c4 * 4) = *(const float4*)(A + (size_t)(row0 + r) * K + kc + c4 * 4);
    }
#pragma unroll
    for (int j = 0; j < 8; ++j) {
      int f = t + 256 * j;
      int kr = f >> 4, c4 = f & 15;
      *(float4*)(Ws + kr * 64 + c4 * 4) = *(const float4*)(W + (size_t)(kc + kr) * N + n0 + c4 * 4);
    }
    __syncthreads();
    for (int k0 = 0; k0 < 128; k0 += 4) {
      float a[4][4], b[4][4];
#pragma unroll
      for (int i = 0; i < 4; ++i) {
        float4 t4 = *(const float4*)(As + (4 * ty + i) * 132 + k0);
        a[i][0] = t4.x; a[i][1] = t4.y; a[i][2] = t4.z; a[i][3] = t4.w;
      }
#pragma unroll
      for (int kk = 0; kk < 4; ++kk) {
        float4 t4 = *(const float4*)(Ws + (k0 + kk) * 64 + 4 * tx);
        b[kk][0] = t4.x; b[kk][1] = t4.y; b[kk][2] = t4.z; b[kk][3] = t4.w;
      }
#pragma unroll
      for (int kk = 0; kk < 4; ++kk)
#pragma unroll
        for (int i = 0; i < 4; ++i)
#pragma unroll
          for (int j = 0; j < 4; ++j)
            acc[i][j] += a[i][kk] * b[kk][j];
    }
    __syncthreads();
  }
  float4 bv = make_float4(0.f, 0.f, 0.f, 0.f);
  if (bias) bv = *(const float4*)(bias + n0 + 4 * tx);
#pragma unroll
  for (int i = 0; i < 4; ++i) {
    float4 r;
    r.x = (acc[i][0] + bv.x) * scale;
    r.y = (acc[i][1] + bv.y) * scale;
    r.z = (acc[i][2] + bv.z) * scale;
    r.w = (acc[i][3] + bv.w) * scale;
    if (relu) { r.x = fmaxf(r.x, 0.f); r.y = fmaxf(r.y, 0.f); r.z = fmaxf(r.z, 0.f); r.w = fmaxf(r.w, 0.f); }
    size_t o = (size_t)(row0 + 4 * ty + i) * N + n0 + 4 * tx;
    if (resid) {
      float4 rv = *(const float4*)(resid + o);
      r.x += rv.x; r.y += rv.y; r.z += rv.z; r.w += rv.w;
    }
    *(float4*)(out + o) = r;
  }
}

// ---------------- flash attention, k-split, 2 q-rows/thread, swizzled LDS ----------------
// grid (256, 2): x = b*16+qt (32 q each), y = split (256 keys each). block 128 = 16 qpairs x 8 h.
// LDS layout: row stride 160 floats; h-segment at offset h*20 -> banks {0,20,8,28,16,4,24,12}: conflict-free.
#define ROWS 160
__global__ __launch_bounds__(128) void attn_k(const float* __restrict__ Q, const float* __restrict__ K,
    const float* __restrict__ V, const float* __restrict__ bias,
    float* __restrict__ accA, float* __restrict__ accB, float* __restrict__ ml) {
  __shared__ float Ks[64 * ROWS];
  __shared__ float Vs[64 * ROWS];
  const int t = threadIdx.x;
  const int b = blockIdx.x >> 4;
  const int qt = blockIdx.x & 15;
  const int s = blockIdx.y;
  const int qp = t >> 3;
  const int h = t & 7;
  const int node0 = b * 512 + qt * 32 + qp * 2;

  float qf0[16], qf1[16];
  {
    const float4* qa = (const float4*)(Q + (size_t)node0 * CC + h * 16);
    const float4* qb = (const float4*)(Q + (size_t)(node0 + 1) * CC + h * 16);
#pragma unroll
    for (int i = 0; i < 4; ++i) {
      float4 a = qa[i], c = qb[i];
      qf0[4*i] = a.x; qf0[4*i+1] = a.y; qf0[4*i+2] = a.z; qf0[4*i+3] = a.w;
      qf1[4*i] = c.x; qf1[4*i+1] = c.y; qf1[4*i+2] = c.z; qf1[4*i+3] = c.w;
    }
  }
  float m0 = -INFINITY, l0 = 0.f, m1 = -INFINITY, l1 = 0.f;
  float ac0[16], ac1[16];
#pragma unroll
  for (int d = 0; d < 16; ++d) { ac0[d] = 0.f; ac1[d] = 0.f; }

  const float* brow0 = bias + (size_t)node0 * 4096 + h;        // +k*8 steps keys
  const float* brow1 = brow0 + 4096;
  const int kbase0 = s * 256;                                   // this split's first key
  float b0c[8], b1c[8], b0n[8], b1n[8];
#pragma unroll
  for (int j = 0; j < 8; ++j) {
    b0c[j] = brow0[(size_t)(kbase0 + j) * 8];
    b1c[j] = brow1[(size_t)(kbase0 + j) * 8];
  }

  const size_t kvbase = (size_t)b * 512 * CC + (size_t)kbase0 * CC;
  for (int kt = 0; kt < 4; ++kt) {
    __syncthreads();
#pragma unroll
    for (int j = 0; j < 16; ++j) {
      int f = t + 128 * j;
      int r = f >> 5, c4 = f & 31;
      int lo = r * ROWS + (c4 >> 2) * 20 + (c4 & 3) * 4;
      size_t go = kvbase + (size_t)(kt * 64 + r) * CC + c4 * 4;
      *(float4*)(Ks + lo) = *(const float4*)(K + go);
      *(float4*)(Vs + lo) = *(const float4*)(V + go);
    }
    __syncthreads();
    for (int c = 0; c < 8; ++c) {
      int lc = kt * 8 + c;
      if (lc < 31) {
#pragma unroll
        for (int j = 0; j < 8; ++j) {
          size_t o = (size_t)(kbase0 + (lc + 1) * 8 + j) * 8;
          b0n[j] = brow0[o];
          b1n[j] = brow1[o];
        }
      }
#pragma unroll
      for (int j = 0; j < 8; ++j) {
        int kk = c * 8 + j;
        const float4* kf = (const float4*)(Ks + kk * ROWS + h * 20);
        float4 k0 = kf[0], k1 = kf[1], k2 = kf[2], k3 = kf[3];
        float kv[16] = {k0.x,k0.y,k0.z,k0.w,k1.x,k1.y,k1.z,k1.w,
                        k2.x,k2.y,k2.z,k2.w,k3.x,k3.y,k3.z,k3.w};
        float s0 = b0c[j], s1 = b1c[j];
#pragma unroll
        for (int d = 0; d < 16; ++d) { s0 += qf0[d] * kv[d]; s1 += qf1[d] * kv[d]; }
        if (s0 > m0) {
          float al = __expf(m0 - s0);
          l0 *= al;
#pragma unroll
          for (int d = 0; d < 16; ++d) ac0[d] *= al;
          m0 = s0;
        }
        if (s1 > m1) {
          float al = __expf(m1 - s1);
          l1 *= al;
#pragma unroll
          for (int d = 0; d < 16; ++d) ac1[d] *= al;
          m1 = s1;
        }
        float p0 = __expf(s0 - m0);
        float p1 = __expf(s1 - m1);
        l0 += p0; l1 += p1;
        const float4* vf = (const float4*)(Vs + kk * ROWS + h * 20);
        float4 v0 = vf[0], v1 = vf[1], v2 = vf[2], v3 = vf[3];
        float vv[16] = {v0.x,v0.y,v0.z,v0.w,v1.x,v1.y,v1.z,v1.w,
                        v2.x,v2.y,v2.z,v2.w,v3.x,v3.y,v3.z,v3.w};
#pragma unroll
        for (int d = 0; d < 16; ++d) { ac0[d] += p0 * vv[d]; ac1[d] += p1 * vv[d]; }
      }
#pragma unroll
      for (int j = 0; j < 8; ++j) { b0c[j] = b0n[j]; b1c[j] = b1n[j]; }
    }
  }
  float* dst = s ? accB : accA;
  float* o0 = dst + (size_t)node0 * CC + h * 16;
  float* o1 = o0 + CC;
#pragma unroll
  for (int i = 0; i < 4; ++i) {
    *(float4*)(o0 + 4 * i) = make_float4(ac0[4*i], ac0[4*i+1], ac0[4*i+2], ac0[4*i+3]);
    *(float4*)(o1 + 4 * i) = make_float4(ac1[4*i], ac1[4*i+1], ac1[4*i+2], ac1[4*i+3]);
  }
  float* mlp = ml + (size_t)s * 65536 * 2;
  int i0 = (node0 * 8 + h) * 2;
  mlp[i0] = m0; mlp[i0 + 1] = l0;
  mlp[i0 + 16] = m1; mlp[i0 + 17] = l1;  // node0+1: +8 (nh) *2
}

__global__ __launch_bounds__(256) void attn_merge_k(const float* __restrict__ accA, const float* __restrict__ accB,
    const float* __restrict__ ml, float* __restrict__ out) {
  int i = blockIdx.x * 256 + threadIdx.x;   // (node, h) pair, 65536 total
  int node = i >> 3, h = i & 7;
  float m0 = ml[i * 2], l0 = ml[i * 2 + 1];
  float m1 = ml[131072 + i * 2], l1 = ml[131072 + i * 2 + 1];
  float M = fmaxf(m0, m1);
  float a0 = __expf(m0 - M), a1 = __expf(m1 - M);
  float inv = 1.f / (l0 * a0 + l1 * a1);
  a0 *= inv; a1 *= inv;
  const float4* pa = (const float4*)(accA + (size_t)node * CC + h * 16);
  const float4* pb = (const float4*)(accB + (size_t)node * CC + h * 16);
  float4* po = (float4*)(out + (size_t)node * CC + h * 16);
#pragma unroll
  for (int k = 0; k < 4; ++k) {
    float4 x = pa[k], y = pb[k];
    po[k] = make_float4(x.x * a0 + y.x * a1, x.y * a0 + y.y * a1,
                        x.z * a0 + y.z * a1, x.w * a0 + y.w * a1);
  }
}

// ---------------- launcher ----------------

extern "C" void kernel_launch(void* const* d_in, const int* in_sizes, int n_in,
                              void* d_out, int out_size, void* d_ws, size_t ws_size,
                              hipStream_t stream) {
  const float* x      = (const float*)d_in[0];
  const int*   ei     = (const int*)d_in[1];
  const float* bias   = (const float*)d_in[3];
  const float* conv_w = (const float*)d_in[4];
  const float* conv_b = (const float*)d_in[5];
  const float* wq = (const float*)d_in[6];
  const float* bq = (const float*)d_in[7];
  const float* wk = (const float*)d_in[8];
  const float* bk = (const float*)d_in[9];
  const float* wv = (const float*)d_in[10];
  const float* bv = (const float*)d_in[11];
  const float* wo = (const float*)d_in[12];
  const float* bo = (const float*)d_in[13];
  const float* w1 = (const float*)d_in[14];
  const float* b1 = (const float*)d_in[15];
  const float* w2 = (const float*)d_in[16];
  const float* b2 = (const float*)d_in[17];
  const float* g1 = (const float*)d_in[18];
  const float* be1 = (const float*)d_in[19];
  const float* g2 = (const float*)d_in[20];
  const float* be2 = (const float*)d_in[21];
  const float* g3 = (const float*)d_in[22];
  const float* be3 = (const float*)d_in[23];
  int E = in_sizes[1] / 2;

  float* ws = (float*)d_ws;
  const size_t NC = (size_t)NN * CC;
  float* xw     = ws;            // also attention final output
  float* h1pre  = ws + NC;
  float* qb     = ws + 2 * NC;
  float* kb     = ws + 3 * NC;
  float* vb     = ws + 4 * NC;
  float* h2pre  = ws + 5 * NC;   // attn split-0 partial acc during attention
  float* outbuf = ws + 6 * NC;   // attn split-1 partial acc during attention
  float* hid    = ws + 2 * NC;
  float* h3pre  = ws + 4 * NC;
  float* st     = ws + 7 * NC;
  float* dinv   = ws + 7 * NC + 1536;
  int*   degi     = (int*)(ws + 7 * NC + 1536 + NN);
  int*   rowstart = degi + NN;
  int*   cursor   = rowstart + NN + 1;
  int*   col      = cursor + NN;
  float* mlbuf    = (float*)(col + E);   // 2 * 65536 * 2 floats

  hipMemsetAsync(degi, 0, NN * sizeof(int), stream);
  hipMemsetAsync(st, 0, 1536 * sizeof(float), stream);

  // ---- GCN branch
  count_deg_int_k<<<(E + 255) / 256, 256, 0, stream>>>(ei + E, degi, E);
  dinv_k<<<NN / 256, 256, 0, stream>>>(degi, dinv, NN);
  scan_k<<<1, 256, 0, stream>>>(degi, rowstart, cursor);
  bucket_k<<<(E + 255) / 256, 256, 0, stream>>>(ei, ei + E, cursor, col, E);
  gemm_k<<<dim3(NN / 64, 2), 256, 0, stream>>>(x, conv_w, nullptr, nullptr, xw, NN, CC, CC, 1.f, 0);
  gather_k<<<NN / 2, 256, 0, stream>>>(rowstart, col, xw, dinv, conv_b, x, h1pre);
  bn_stats_k<<<NN / 64, 256, 0, stream>>>(h1pre, st + 0, st + 128);

  // ---- attention branch
  gemm_k<<<dim3(NN / 64, 2), 256, 0, stream>>>(x, wq, bq, nullptr, qb, NN, CC, CC, 0.25f, 0);
  gemm_k<<<dim3(NN / 64, 2), 256, 0, stream>>>(x, wk, bk, nullptr, kb, NN, CC, CC, 1.f, 0);
  gemm_k<<<dim3(NN / 64, 2), 256, 0, stream>>>(x, wv, bv, nullptr, vb, NN, CC, CC, 1.f, 0);
  attn_k<<<dim3(256, 2), 128, 0, stream>>>(qb, kb, vb, bias, h2pre, outbuf, mlbuf);
  attn_merge_k<<<65536 / 256, 256, 0, stream>>>(h2pre, outbuf, mlbuf, xw);
  gemm_k<<<dim3(NN / 64, 2), 256, 0, stream>>>(xw, wo, bo, x, h2pre, NN, CC, CC, 1.f, 0);
  bn_stats_k<<<NN / 64, 256, 0, stream>>>(h2pre, st + 256, st + 384);

  // ---- combine + MLP
  bn_finalize_k<<<1, 128, 0, stream>>>(st + 0, st + 128, g1, be1, st + 768, st + 896);
  bn_finalize_k<<<1, 128, 0, stream>>>(st + 256, st + 384, g2, be2, st + 1024, st + 1152);
  combine_k<<<NC / 256, 256, 0, stream>>>(h1pre, h2pre, st + 768, st + 896, st + 1024, st + 1152, outbuf);
  gemm_k<<<dim3(NN / 64, 4), 256, 0, stream>>>(outbuf, w1, b1, nullptr, hid, NN, 2 * CC, CC, 1.f, 1);
  gemm_k<<<dim3(NN / 64, 2), 256, 0, stream>>>(hid, w2, b2, outbuf, h3pre, NN, CC, 2 * CC, 1.f, 0);
  bn_stats_k<<<NN / 64, 256, 0, stream>>>(h3pre, st + 512, st + 640);
  bn_finalize_k<<<1, 128, 0, stream>>>(st + 512, st + 640, g3, be3, st + 1280, st + 1408);
  bn_apply_k<<<NC / 256, 256, 0, stream>>>(h3pre, st + 1280, st + 1408, (float*)d_out);
}